// Round 6
// baseline (22545.081 us; speedup 1.0000x reference)
//
#include <hip/hip_runtime.h>
#include <hip/hip_bf16.h>

#define DIN 64
#define FF 32
#define MAX_OUTER 8

__device__ __forceinline__ float sigm(float x) {
  return 1.0f / (1.0f + __expf(-x));
}
__device__ __forceinline__ float tanh_fast(float x) {
  float e = __expf(2.0f * x);
  return 1.0f - 2.0f / (e + 1.0f);
}

// Detect int64 vs int32 for idx/lens (int64 -> odd int32 slots all zero).
__global__ void detect_dtypes(const int* __restrict__ idx_raw,
                              const int* __restrict__ lens_raw,
                              int* __restrict__ flags) {
  __shared__ int zi, zl;
  if (threadIdx.x == 0) { zi = 0; zl = 0; }
  __syncthreads();
  int j = threadIdx.x;  // 0..255
  if (idx_raw[2 * j + 1] == 0)  atomicAdd(&zi, 1);
  if (lens_raw[2 * j + 1] == 0) atomicAdd(&zl, 1);
  __syncthreads();
  if (threadIdx.x == 0) {
    flags[0] = (zi >= 250) ? 1 : 0;
    flags[1] = (zl >= 250) ? 1 : 0;
  }
}

__global__ __launch_bounds__(256) void cvt_ints(const void* __restrict__ src,
                                                int* __restrict__ dst,
                                                const int* __restrict__ flags,
                                                int which, long n) {
  long i = (long)blockIdx.x * 256 + threadIdx.x;
  if (i >= n) return;
  int is64 = flags[which];
  dst[i] = is64 ? (int)((const long long*)src)[i] : ((const int*)src)[i];
}

// One GRU step per-lane; weight addresses wave-uniform -> scalar loads.
__device__ __forceinline__ void gru_gates(
    const float* __restrict__ Wi, const float* __restrict__ Wh,
    const float* __restrict__ bi, const float* __restrict__ bh,
    const float* __restrict__ x, float* __restrict__ h) {
  float hn[FF];
#pragma unroll
  for (int g = 0; g < FF; ++g) {
    float ar   = bi[g] + bh[g];
    float az   = bi[FF + g] + bh[FF + g];
    float an_i = bi[2 * FF + g];
    float an_h = bh[2 * FF + g];
#pragma unroll
    for (int k = 0; k < FF; ++k) {
      const float xk = x[k];
      const float hk = h[k];
      ar   = fmaf(xk, Wi[g * FF + k], ar);
      ar   = fmaf(hk, Wh[g * FF + k], ar);
      az   = fmaf(xk, Wi[(FF + g) * FF + k], az);
      az   = fmaf(hk, Wh[(FF + g) * FF + k], az);
      an_i = fmaf(xk, Wi[(2 * FF + g) * FF + k], an_i);
      an_h = fmaf(hk, Wh[(2 * FF + g) * FF + k], an_h);
    }
    float r = sigm(ar);
    float z = sigm(az);
    float n = tanh_fast(fmaf(r, an_h, an_i));
    hn[g] = fmaf(z, h[g] - n, n);  // (1-z)*n + z*h
  }
#pragma unroll
  for (int g = 0; g < FF; ++g) h[g] = hn[g];
}

__global__ __launch_bounds__(256) void init_proj(
    const float* __restrict__ raw,
    const float* __restrict__ W, const float* __restrict__ b,
    float* __restrict__ out, int nrows) {
  int i = blockIdx.x * blockDim.x + threadIdx.x;
  if (i >= nrows) return;
  float x[DIN];
  const float4* rp = (const float4*)(raw + (size_t)i * DIN);
#pragma unroll
  for (int q = 0; q < DIN / 4; ++q) {
    float4 v = rp[q];
    x[q * 4 + 0] = v.x; x[q * 4 + 1] = v.y; x[q * 4 + 2] = v.z; x[q * 4 + 3] = v.w;
  }
  float acc[FF];
#pragma unroll
  for (int j = 0; j < FF; ++j) acc[j] = b[j];
#pragma unroll
  for (int k = 0; k < DIN; ++k) {
    float xk = x[k];
#pragma unroll
    for (int j = 0; j < FF; ++j) acc[j] = fmaf(xk, W[k * FF + j], acc[j]);
  }
  float4* op = (float4*)(out + (size_t)i * FF);
#pragma unroll
  for (int j = 0; j < FF; j += 4) {
    float4 v;
    v.x = fmaxf(acc[j + 0], 0.0f);
    v.y = fmaxf(acc[j + 1], 0.0f);
    v.z = fmaxf(acc[j + 2], 0.0f);
    v.w = fmaxf(acc[j + 3], 0.0f);
    op[j / 4] = v;
  }
}

__global__ __launch_bounds__(256) void path_step(
    const float* __restrict__ c_state, float* __restrict__ p_state,
    float* __restrict__ agg, const int* __restrict__ idx,
    const int* __restrict__ lens,
    const float* __restrict__ Wi, const float* __restrict__ Wh,
    const float* __restrict__ bi, const float* __restrict__ bh,
    int P, int C, int L, const int* __restrict__ ns_ptr, int use_mem, int s) {
  int ns = use_mem ? *ns_ptr : 5;
  if (ns < 1 || ns > MAX_OUTER) ns = 5;
  if (s >= ns) return;
  int i = blockIdx.x * blockDim.x + threadIdx.x;
  if (i >= P) return;
  int len = lens[i];
  if (len > L - 1) len = L - 1;

  float h[FF];
  const float4* pp = (const float4*)(p_state + (size_t)i * FF);
#pragma unroll
  for (int q = 0; q < FF / 4; ++q) {
    float4 v = pp[q];
    h[q * 4 + 0] = v.x; h[q * 4 + 1] = v.y; h[q * 4 + 2] = v.z; h[q * 4 + 3] = v.w;
  }

#pragma unroll 1
  for (int t = 0; t < L; ++t) {
    if (t > len) break;
    int ch = idx[(size_t)i * L + t];
    if (ch < 0) ch = 0;
    if (ch >= C) ch = C - 1;  // jax gather clips
    float x[FF];
    const float4* cp = (const float4*)(c_state + (size_t)ch * FF);
#pragma unroll
    for (int q = 0; q < FF / 4; ++q) {
      float4 v = cp[q];
      x[q * 4 + 0] = v.x; x[q * 4 + 1] = v.y; x[q * 4 + 2] = v.z; x[q * 4 + 3] = v.w;
    }
    gru_gates(Wi, Wh, bi, bh, x, h);
  }

  float4* op = (float4*)(p_state + (size_t)i * FF);
#pragma unroll
  for (int q = 0; q < FF / 4; ++q) {
    float4 v;
    v.x = h[q * 4 + 0]; v.y = h[q * 4 + 1]; v.z = h[q * 4 + 2]; v.w = h[q * 4 + 3];
    op[q] = v;
  }

#pragma unroll 1
  for (int t = 0; t <= len && t < L; ++t) {
    int ch = idx[(size_t)i * L + t];
    if (ch < 0 || ch >= C) continue;  // segment_sum drops OOB
    float* ap = agg + (size_t)ch * FF;
#pragma unroll
    for (int j = 0; j < FF; ++j) atomicAdd(ap + j, h[j]);
  }
}

__global__ __launch_bounds__(256) void chan_step(
    float* __restrict__ c_state, const float* __restrict__ agg,
    const float* __restrict__ Wi, const float* __restrict__ Wh,
    const float* __restrict__ bi, const float* __restrict__ bh,
    int C, const int* __restrict__ ns_ptr, int use_mem, int s) {
  int ns = use_mem ? *ns_ptr : 5;
  if (ns < 1 || ns > MAX_OUTER) ns = 5;
  if (s >= ns) return;
  int i = blockIdx.x * blockDim.x + threadIdx.x;
  if (i >= C) return;

  float x[FF], h[FF];
  const float4* apv = (const float4*)(agg + (size_t)i * FF);
  const float4* cpv = (const float4*)(c_state + (size_t)i * FF);
#pragma unroll
  for (int q = 0; q < FF / 4; ++q) {
    float4 a = apv[q];
    x[q * 4 + 0] = a.x; x[q * 4 + 1] = a.y; x[q * 4 + 2] = a.z; x[q * 4 + 3] = a.w;
    float4 c = cpv[q];
    h[q * 4 + 0] = c.x; h[q * 4 + 1] = c.y; h[q * 4 + 2] = c.z; h[q * 4 + 3] = c.w;
  }
  gru_gates(Wi, Wh, bi, bh, x, h);
  float4* op = (float4*)(c_state + (size_t)i * FF);
#pragma unroll
  for (int q = 0; q < FF / 4; ++q) {
    float4 v;
    v.x = h[q * 4 + 0]; v.y = h[q * 4 + 1]; v.z = h[q * 4 + 2]; v.w = h[q * 4 + 3];
    op[q] = v;
  }
}

// fp32 -> fp32 copy (output is FLOAT32: reference returns fp32 arrays)
__global__ void copy_out(const float* __restrict__ src,
                         float* __restrict__ dst, long n) {
  long i = (long)blockIdx.x * 256 + threadIdx.x;
  if (i >= n) return;
  dst[i] = src[i];
}

// Diagnostic: out[0] = 1024*(64+code) if a host-visible anomaly was detected.
__global__ void beacon(float* out, int code) {
  out[0] = (float)(1024 * (64 + code));
}

extern "C" void kernel_launch(void* const* d_in, const int* in_sizes, int n_in,
                              void* d_out, int out_size, void* d_ws, size_t ws_size,
                              hipStream_t stream) {
  int base = 5, use_mem = 1;
  if (n_in == 16) { base = 4; use_mem = 0; }
  const float* path_raw = (const float*)d_in[0];
  const float* chan_raw = (const float*)d_in[1];
  const void* idx_raw  = d_in[2];
  const void* lens_raw = d_in[3];
  const int* ns_ptr = use_mem ? (const int*)d_in[4] : (const int*)d_in[0];
  const float* Wp  = (const float*)d_in[base + 0];
  const float* bp  = (const float*)d_in[base + 1];
  const float* Wc  = (const float*)d_in[base + 2];
  const float* bc  = (const float*)d_in[base + 3];
  const float* Wi1 = (const float*)d_in[base + 4];
  const float* Wh1 = (const float*)d_in[base + 5];
  const float* bi1 = (const float*)d_in[base + 6];
  const float* bh1 = (const float*)d_in[base + 7];
  const float* Wi2 = (const float*)d_in[base + 8];
  const float* Wh2 = (const float*)d_in[base + 9];
  const float* bi2 = (const float*)d_in[base + 10];
  const float* bh2 = (const float*)d_in[base + 11];

  long P = in_sizes[0] / DIN;
  long C = in_sizes[1] / DIN;
  long L = (P > 0) ? (in_sizes[2] / P) : 8;

  int anomaly = 0;
  if (n_in != 17 && n_in != 16) anomaly |= 1;
  if (P <= 0 || C <= 0 || L < 1 || L > 64) anomaly |= 2;
  if (P > 0 && in_sizes[3] != (int)P) anomaly |= 4;
  if ((long)out_size != (P + C) * FF) anomaly |= 8;

  long PL = P * L;
  int* idx32  = (int*)d_ws;
  int* lens32 = idx32 + PL;
  int* flags  = lens32 + P;
  float* fbase = (float*)(flags + 16);
  size_t full_bytes    = ((size_t)(PL + P + 16) + (size_t)(P + 2 * C) * FF) * 4;
  size_t partial_bytes = ((size_t)(PL + P + 16) + (size_t)P * FF) * 4;

  float* p_state = fbase;
  float* c_state;
  float* agg;
  bool overlay = (ws_size < full_bytes);
  if (!overlay) {
    c_state = p_state + (size_t)P * FF;
    agg     = c_state + (size_t)C * FF;
  } else {
    // overlay scratch at start of d_out: 2*C*FF fp32 (12.8MB) <= out bytes (32MB)
    c_state = (float*)d_out;
    agg     = c_state + (size_t)C * FF;
    if (ws_size < partial_bytes) anomaly |= 16;
  }

  detect_dtypes<<<1, 256, 0, stream>>>((const int*)idx_raw, (const int*)lens_raw, flags);
  cvt_ints<<<(int)((PL + 255) / 256), 256, 0, stream>>>(idx_raw, idx32, flags, 0, PL);
  cvt_ints<<<(int)((P + 255) / 256), 256, 0, stream>>>(lens_raw, lens32, flags, 1, P);

  init_proj<<<(int)((P + 255) / 256), 256, 0, stream>>>(path_raw, Wp, bp, p_state, (int)P);
  init_proj<<<(int)((C + 255) / 256), 256, 0, stream>>>(chan_raw, Wc, bc, c_state, (int)C);

  for (int s = 0; s < MAX_OUTER; ++s) {
    hipMemsetAsync(agg, 0, (size_t)C * FF * sizeof(float), stream);
    path_step<<<(int)((P + 255) / 256), 256, 0, stream>>>(
        c_state, p_state, agg, idx32, lens32, Wi1, Wh1, bi1, bh1,
        (int)P, (int)C, (int)L, ns_ptr, use_mem, s);
    chan_step<<<(int)((C + 255) / 256), 256, 0, stream>>>(
        c_state, agg, Wi2, Wh2, bi2, bh2, (int)C, ns_ptr, use_mem, s);
  }

  float* out = (float*)d_out;
  // c-part first (overlay-safe: reads bytes [0,6.4M), writes [25.6M,32M))
  copy_out<<<(int)((C * FF + 255) / 256), 256, 0, stream>>>(
      c_state, out + (size_t)P * FF, C * FF);
  copy_out<<<(int)((P * FF + 255) / 256), 256, 0, stream>>>(p_state, out, P * FF);

  if (anomaly) beacon<<<1, 1, 0, stream>>>(out, anomaly);
}

// Round 7
// 8464.909 us; speedup vs baseline: 2.6634x; 2.6634x over previous
//
#include <hip/hip_runtime.h>
#include <hip/hip_bf16.h>

#define DIN 64
#define FF 32
#define MAX_OUTER 8

__device__ __forceinline__ float sigm(float x) {
  return 1.0f / (1.0f + __expf(-x));
}
__device__ __forceinline__ float tanh_fast(float x) {
  float e = __expf(2.0f * x);
  return 1.0f - 2.0f / (e + 1.0f);
}

// int32/int64 dual reader (dtype decided at runtime by detect_dtypes)
__device__ __forceinline__ int iread(const void* src, long i, int is64) {
  return is64 ? (int)((const long long*)src)[i] : ((const int*)src)[i];
}

// Detect int64 vs int32 for idx/lens (int64 -> odd int32 slots all zero).
__global__ void detect_dtypes(const int* __restrict__ idx_raw,
                              const int* __restrict__ lens_raw,
                              int* __restrict__ flags) {
  __shared__ int zi, zl;
  if (threadIdx.x == 0) { zi = 0; zl = 0; }
  __syncthreads();
  int j = threadIdx.x;  // 0..255
  if (idx_raw[2 * j + 1] == 0)  atomicAdd(&zi, 1);
  if (lens_raw[2 * j + 1] == 0) atomicAdd(&zl, 1);
  __syncthreads();
  if (threadIdx.x == 0) {
    flags[0] = (zi >= 250) ? 1 : 0;
    flags[1] = (zl >= 250) ? 1 : 0;
  }
}

// One GRU step per-lane; weight addresses wave-uniform -> scalar loads.
__device__ __forceinline__ void gru_gates(
    const float* __restrict__ Wi, const float* __restrict__ Wh,
    const float* __restrict__ bi, const float* __restrict__ bh,
    const float* __restrict__ x, float* __restrict__ h) {
  float hn[FF];
#pragma unroll
  for (int g = 0; g < FF; ++g) {
    float ar   = bi[g] + bh[g];
    float az   = bi[FF + g] + bh[FF + g];
    float an_i = bi[2 * FF + g];
    float an_h = bh[2 * FF + g];
#pragma unroll
    for (int k = 0; k < FF; ++k) {
      const float xk = x[k];
      const float hk = h[k];
      ar   = fmaf(xk, Wi[g * FF + k], ar);
      ar   = fmaf(hk, Wh[g * FF + k], ar);
      az   = fmaf(xk, Wi[(FF + g) * FF + k], az);
      az   = fmaf(hk, Wh[(FF + g) * FF + k], az);
      an_i = fmaf(xk, Wi[(2 * FF + g) * FF + k], an_i);
      an_h = fmaf(hk, Wh[(2 * FF + g) * FF + k], an_h);
    }
    float r = sigm(ar);
    float z = sigm(az);
    float n = tanh_fast(fmaf(r, an_h, an_i));
    hn[g] = fmaf(z, h[g] - n, n);  // (1-z)*n + z*h
  }
#pragma unroll
  for (int g = 0; g < FF; ++g) h[g] = hn[g];
}

__global__ __launch_bounds__(256) void init_proj(
    const float* __restrict__ raw,
    const float* __restrict__ W, const float* __restrict__ b,
    float* __restrict__ out, int nrows) {
  int i = blockIdx.x * blockDim.x + threadIdx.x;
  if (i >= nrows) return;
  float x[DIN];
  const float4* rp = (const float4*)(raw + (size_t)i * DIN);
#pragma unroll
  for (int q = 0; q < DIN / 4; ++q) {
    float4 v = rp[q];
    x[q * 4 + 0] = v.x; x[q * 4 + 1] = v.y; x[q * 4 + 2] = v.z; x[q * 4 + 3] = v.w;
  }
  float acc[FF];
#pragma unroll
  for (int j = 0; j < FF; ++j) acc[j] = b[j];
#pragma unroll
  for (int k = 0; k < DIN; ++k) {
    float xk = x[k];
#pragma unroll
    for (int j = 0; j < FF; ++j) acc[j] = fmaf(xk, W[k * FF + j], acc[j]);
  }
  float4* op = (float4*)(out + (size_t)i * FF);
#pragma unroll
  for (int j = 0; j < FF; j += 4) {
    float4 v;
    v.x = fmaxf(acc[j + 0], 0.0f);
    v.y = fmaxf(acc[j + 1], 0.0f);
    v.z = fmaxf(acc[j + 2], 0.0f);
    v.w = fmaxf(acc[j + 3], 0.0f);
    op[j / 4] = v;
  }
}

// ---- CSR build (once per launch; idx/lens are invariant across outer steps) ----

// counts[ch] += 1 per (path, t<=len): 900K int atomics (NOT 29M float ones)
__global__ __launch_bounds__(256) void count_contribs(
    const void* __restrict__ idx_raw, const void* __restrict__ lens_raw,
    const int* __restrict__ flags, int* __restrict__ cnt, int P, int C, int L) {
  int i = blockIdx.x * blockDim.x + threadIdx.x;
  if (i >= P) return;
  int i64 = flags[0], l64 = flags[1];
  int len = iread(lens_raw, i, l64);
  if (len > L - 1) len = L - 1;
  for (int t = 0; t <= len; ++t) {
    int ch = iread(idx_raw, (long)i * L + t, i64);
    if (ch < 0) ch = 0;
    if (ch >= C) ch = C - 1;
    atomicAdd(&cnt[ch], 1);
  }
}

// single-block exclusive scan of cnt[0..C) -> rowstart[0..C], cursor=rowstart
__global__ __launch_bounds__(1024) void scan_counts(
    const int* __restrict__ cnt, int* __restrict__ rowstart,
    int* __restrict__ cursor, int C) {
  __shared__ int buf[1024];
  __shared__ int carry;
  if (threadIdx.x == 0) carry = 0;
  __syncthreads();
  for (int base = 0; base < C; base += 1024) {
    int i = base + threadIdx.x;
    int v = (i < C) ? cnt[i] : 0;
    buf[threadIdx.x] = v;
    __syncthreads();
    for (int off = 1; off < 1024; off <<= 1) {
      int t = (threadIdx.x >= off) ? buf[threadIdx.x - off] : 0;
      __syncthreads();
      buf[threadIdx.x] += t;
      __syncthreads();
    }
    int excl = buf[threadIdx.x] - v;
    if (i < C) { rowstart[i] = carry + excl; cursor[i] = carry + excl; }
    __syncthreads();
    if (threadIdx.x == 0) carry += buf[1023];
    __syncthreads();
  }
  if (threadIdx.x == 0) rowstart[C] = carry;
}

// entries[slot] = path, slot from per-channel cursor
__global__ __launch_bounds__(256) void fill_entries(
    const void* __restrict__ idx_raw, const void* __restrict__ lens_raw,
    const int* __restrict__ flags, int* __restrict__ cursor,
    int* __restrict__ entries, int P, int C, int L) {
  int i = blockIdx.x * blockDim.x + threadIdx.x;
  if (i >= P) return;
  int i64 = flags[0], l64 = flags[1];
  int len = iread(lens_raw, i, l64);
  if (len > L - 1) len = L - 1;
  for (int t = 0; t <= len; ++t) {
    int ch = iread(idx_raw, (long)i * L + t, i64);
    if (ch < 0) ch = 0;
    if (ch >= C) ch = C - 1;
    int slot = atomicAdd(&cursor[ch], 1);
    entries[slot] = i;
  }
}

// ---- per-outer-step kernels (guarded by device-side num_steps) ----

// GRU scan over t with h in registers; p updated in place (p lives in d_out)
__global__ __launch_bounds__(256) void path_step(
    const float* __restrict__ c_state, float* __restrict__ p_state,
    const void* __restrict__ idx_raw, const void* __restrict__ lens_raw,
    const int* __restrict__ flags,
    const float* __restrict__ Wi, const float* __restrict__ Wh,
    const float* __restrict__ bi, const float* __restrict__ bh,
    int P, int C, int L, const int* __restrict__ ns_ptr, int use_mem, int s) {
  int ns = use_mem ? *ns_ptr : 5;
  if (ns < 1 || ns > MAX_OUTER) ns = 5;
  if (s >= ns) return;
  int i = blockIdx.x * blockDim.x + threadIdx.x;
  if (i >= P) return;
  int i64 = flags[0], l64 = flags[1];
  int len = iread(lens_raw, i, l64);
  if (len > L - 1) len = L - 1;

  float h[FF];
  const float4* pp = (const float4*)(p_state + (size_t)i * FF);
#pragma unroll
  for (int q = 0; q < FF / 4; ++q) {
    float4 v = pp[q];
    h[q * 4 + 0] = v.x; h[q * 4 + 1] = v.y; h[q * 4 + 2] = v.z; h[q * 4 + 3] = v.w;
  }

#pragma unroll 1
  for (int t = 0; t <= len && t < L; ++t) {
    int ch = iread(idx_raw, (long)i * L + t, i64);
    if (ch < 0) ch = 0;
    if (ch >= C) ch = C - 1;  // jax gather clips
    float x[FF];
    const float4* cp = (const float4*)(c_state + (size_t)ch * FF);
#pragma unroll
    for (int q = 0; q < FF / 4; ++q) {
      float4 v = cp[q];
      x[q * 4 + 0] = v.x; x[q * 4 + 1] = v.y; x[q * 4 + 2] = v.z; x[q * 4 + 3] = v.w;
    }
    gru_gates(Wi, Wh, bi, bh, x, h);
  }

  float4* op = (float4*)(p_state + (size_t)i * FF);
#pragma unroll
  for (int q = 0; q < FF / 4; ++q) {
    float4 v;
    v.x = h[q * 4 + 0]; v.y = h[q * 4 + 1]; v.z = h[q * 4 + 2]; v.w = h[q * 4 + 3];
    op[q] = v;
  }
}

// atomic-free segment sum: 32 lanes per channel sum contributor p-rows
__global__ __launch_bounds__(256) void agg_gather(
    const float* __restrict__ p_state, const int* __restrict__ rowstart,
    const int* __restrict__ entries, float* __restrict__ agg,
    int C, const int* __restrict__ ns_ptr, int use_mem, int s) {
  int ns = use_mem ? *ns_ptr : 5;
  if (ns < 1 || ns > MAX_OUTER) ns = 5;
  if (s >= ns) return;
  int c = blockIdx.x * 8 + (threadIdx.x >> 5);
  int j = threadIdx.x & 31;
  if (c >= C) return;
  int rs = rowstart[c], re = rowstart[c + 1];
  float acc = 0.0f;
  for (int e = rs; e < re; ++e) {
    int path = entries[e];
    acc += p_state[(size_t)path * FF + j];
  }
  agg[(size_t)c * FF + j] = acc;
}

__global__ __launch_bounds__(256) void chan_step(
    float* __restrict__ c_state, const float* __restrict__ agg,
    const float* __restrict__ Wi, const float* __restrict__ Wh,
    const float* __restrict__ bi, const float* __restrict__ bh,
    int C, const int* __restrict__ ns_ptr, int use_mem, int s) {
  int ns = use_mem ? *ns_ptr : 5;
  if (ns < 1 || ns > MAX_OUTER) ns = 5;
  if (s >= ns) return;
  int i = blockIdx.x * blockDim.x + threadIdx.x;
  if (i >= C) return;

  float x[FF], h[FF];
  const float4* apv = (const float4*)(agg + (size_t)i * FF);
  const float4* cpv = (const float4*)(c_state + (size_t)i * FF);
#pragma unroll
  for (int q = 0; q < FF / 4; ++q) {
    float4 a = apv[q];
    x[q * 4 + 0] = a.x; x[q * 4 + 1] = a.y; x[q * 4 + 2] = a.z; x[q * 4 + 3] = a.w;
    float4 c = cpv[q];
    h[q * 4 + 0] = c.x; h[q * 4 + 1] = c.y; h[q * 4 + 2] = c.z; h[q * 4 + 3] = c.w;
  }
  gru_gates(Wi, Wh, bi, bh, x, h);
  float4* op = (float4*)(c_state + (size_t)i * FF);
#pragma unroll
  for (int q = 0; q < FF / 4; ++q) {
    float4 v;
    v.x = h[q * 4 + 0]; v.y = h[q * 4 + 1]; v.z = h[q * 4 + 2]; v.w = h[q * 4 + 3];
    op[q] = v;
  }
}

// Diagnostic: out[0] = 1024*(64+code) if a host-visible anomaly was detected.
__global__ void beacon(float* out, int code) {
  out[0] = (float)(1024 * (64 + code));
}

extern "C" void kernel_launch(void* const* d_in, const int* in_sizes, int n_in,
                              void* d_out, int out_size, void* d_ws, size_t ws_size,
                              hipStream_t stream) {
  int base = 5, use_mem = 1;
  if (n_in == 16) { base = 4; use_mem = 0; }
  const float* path_raw = (const float*)d_in[0];
  const float* chan_raw = (const float*)d_in[1];
  const void* idx_raw  = d_in[2];
  const void* lens_raw = d_in[3];
  const int* ns_ptr = use_mem ? (const int*)d_in[4] : (const int*)d_in[0];
  const float* Wp  = (const float*)d_in[base + 0];
  const float* bp  = (const float*)d_in[base + 1];
  const float* Wc  = (const float*)d_in[base + 2];
  const float* bc  = (const float*)d_in[base + 3];
  const float* Wi1 = (const float*)d_in[base + 4];
  const float* Wh1 = (const float*)d_in[base + 5];
  const float* bi1 = (const float*)d_in[base + 6];
  const float* bh1 = (const float*)d_in[base + 7];
  const float* Wi2 = (const float*)d_in[base + 8];
  const float* Wh2 = (const float*)d_in[base + 9];
  const float* bi2 = (const float*)d_in[base + 10];
  const float* bh2 = (const float*)d_in[base + 11];

  long P = in_sizes[0] / DIN;
  long C = in_sizes[1] / DIN;
  long L = (P > 0) ? (in_sizes[2] / P) : 8;
  long PL = P * L;

  int anomaly = 0;
  if (n_in != 17 && n_in != 16) anomaly |= 1;
  if (P <= 0 || C <= 0 || L < 1 || L > 64) anomaly |= 2;
  if (P > 0 && in_sizes[3] != (int)P) anomaly |= 4;
  if ((long)out_size != (P + C) * FF) anomaly |= 8;

  // p_state and c_state live DIRECTLY in d_out (output is fp32, same layout)
  float* out_f   = (float*)d_out;
  float* p_state = out_f;                     // P*FF floats
  float* c_state = out_f + (size_t)P * FF;    // C*FF floats

  // workspace: flags | rowstart[C+1] | cursor[C] | entries[PL] | agg[C*FF]
  int* flags    = (int*)d_ws;
  int* rowstart = flags + 16;
  int* cursor   = rowstart + (C + 1);
  int* entries  = cursor + C;
  float* agg    = (float*)(entries + PL);
  size_t need = ((size_t)16 + (C + 1) + C + PL + (size_t)C * FF) * 4;
  if (ws_size < need) anomaly |= 16;

  detect_dtypes<<<1, 256, 0, stream>>>((const int*)idx_raw, (const int*)lens_raw, flags);

  // initial projections straight into d_out
  init_proj<<<(int)((P + 255) / 256), 256, 0, stream>>>(path_raw, Wp, bp, p_state, (int)P);
  init_proj<<<(int)((C + 255) / 256), 256, 0, stream>>>(chan_raw, Wc, bc, c_state, (int)C);

  // CSR build (idx/lens invariant across outer steps)
  hipMemsetAsync(cursor, 0, (size_t)C * sizeof(int), stream);
  count_contribs<<<(int)((P + 255) / 256), 256, 0, stream>>>(
      idx_raw, lens_raw, flags, cursor, (int)P, (int)C, (int)L);
  scan_counts<<<1, 1024, 0, stream>>>(cursor, rowstart, cursor, (int)C);
  fill_entries<<<(int)((P + 255) / 256), 256, 0, stream>>>(
      idx_raw, lens_raw, flags, cursor, entries, (int)P, (int)C, (int)L);

  for (int s = 0; s < MAX_OUTER; ++s) {
    path_step<<<(int)((P + 255) / 256), 256, 0, stream>>>(
        c_state, p_state, idx_raw, lens_raw, flags,
        Wi1, Wh1, bi1, bh1, (int)P, (int)C, (int)L, ns_ptr, use_mem, s);
    agg_gather<<<(int)((C + 7) / 8), 256, 0, stream>>>(
        p_state, rowstart, entries, agg, (int)C, ns_ptr, use_mem, s);
    chan_step<<<(int)((C + 255) / 256), 256, 0, stream>>>(
        c_state, agg, Wi2, Wh2, bi2, bh2, (int)C, ns_ptr, use_mem, s);
  }

  if (anomaly) beacon<<<1, 1, 0, stream>>>(out_f, anomaly);
}

// Round 8
// 6344.796 us; speedup vs baseline: 3.5533x; 1.3341x over previous
//
#include <hip/hip_runtime.h>
#include <hip/hip_bf16.h>

#define DIN 64
#define FF 32
#define MAX_OUTER 8

__device__ __forceinline__ float sigm(float x) {
  return 1.0f / (1.0f + __expf(-x));
}
__device__ __forceinline__ float tanh_fast(float x) {
  float e = __expf(2.0f * x);
  return 1.0f - 2.0f / (e + 1.0f);
}

// int32/int64 dual reader (dtype decided at runtime by detect_dtypes)
__device__ __forceinline__ int iread(const void* src, long i, int is64) {
  return is64 ? (int)((const long long*)src)[i] : ((const int*)src)[i];
}

__global__ void detect_dtypes(const int* __restrict__ idx_raw,
                              const int* __restrict__ lens_raw,
                              int* __restrict__ flags) {
  __shared__ int zi, zl;
  if (threadIdx.x == 0) { zi = 0; zl = 0; }
  __syncthreads();
  int j = threadIdx.x;  // 0..255
  if (idx_raw[2 * j + 1] == 0)  atomicAdd(&zi, 1);
  if (lens_raw[2 * j + 1] == 0) atomicAdd(&zl, 1);
  __syncthreads();
  if (threadIdx.x == 0) {
    flags[0] = (zi >= 250) ? 1 : 0;
    flags[1] = (zl >= 250) ? 1 : 0;
  }
}

// One GRU step per-lane; weight addresses wave-uniform -> scalar loads.
__device__ __forceinline__ void gru_gates(
    const float* __restrict__ Wi, const float* __restrict__ Wh,
    const float* __restrict__ bi, const float* __restrict__ bh,
    const float* __restrict__ x, float* __restrict__ h) {
  float hn[FF];
#pragma unroll
  for (int g = 0; g < FF; ++g) {
    float ar   = bi[g] + bh[g];
    float az   = bi[FF + g] + bh[FF + g];
    float an_i = bi[2 * FF + g];
    float an_h = bh[2 * FF + g];
#pragma unroll
    for (int k = 0; k < FF; ++k) {
      const float xk = x[k];
      const float hk = h[k];
      ar   = fmaf(xk, Wi[g * FF + k], ar);
      ar   = fmaf(hk, Wh[g * FF + k], ar);
      az   = fmaf(xk, Wi[(FF + g) * FF + k], az);
      az   = fmaf(hk, Wh[(FF + g) * FF + k], az);
      an_i = fmaf(xk, Wi[(2 * FF + g) * FF + k], an_i);
      an_h = fmaf(hk, Wh[(2 * FF + g) * FF + k], an_h);
    }
    float r = sigm(ar);
    float z = sigm(az);
    float n = tanh_fast(fmaf(r, an_h, an_i));
    hn[g] = fmaf(z, h[g] - n, n);  // (1-z)*n + z*h
  }
#pragma unroll
  for (int g = 0; g < FF; ++g) h[g] = hn[g];
}

__global__ __launch_bounds__(256) void init_proj(
    const float* __restrict__ raw,
    const float* __restrict__ W, const float* __restrict__ b,
    float* __restrict__ out, int nrows) {
  int i = blockIdx.x * blockDim.x + threadIdx.x;
  if (i >= nrows) return;
  float x[DIN];
  const float4* rp = (const float4*)(raw + (size_t)i * DIN);
#pragma unroll
  for (int q = 0; q < DIN / 4; ++q) {
    float4 v = rp[q];
    x[q * 4 + 0] = v.x; x[q * 4 + 1] = v.y; x[q * 4 + 2] = v.z; x[q * 4 + 3] = v.w;
  }
  float acc[FF];
#pragma unroll
  for (int j = 0; j < FF; ++j) acc[j] = b[j];
#pragma unroll
  for (int k = 0; k < DIN; ++k) {
    float xk = x[k];
#pragma unroll
    for (int j = 0; j < FF; ++j) acc[j] = fmaf(xk, W[k * FF + j], acc[j]);
  }
  float4* op = (float4*)(out + (size_t)i * FF);
#pragma unroll
  for (int j = 0; j < FF; j += 4) {
    float4 v;
    v.x = fmaxf(acc[j + 0], 0.0f);
    v.y = fmaxf(acc[j + 1], 0.0f);
    v.z = fmaxf(acc[j + 2], 0.0f);
    v.w = fmaxf(acc[j + 3], 0.0f);
    op[j / 4] = v;
  }
}

// ---- one-time index preprocessing (idx/lens invariant across outer steps) ----

// counts[ch] += 1 per (path, t<=len)
__global__ __launch_bounds__(256) void count_contribs(
    const void* __restrict__ idx_raw, const void* __restrict__ lens_raw,
    const int* __restrict__ flags, int* __restrict__ cnt, int P, int C, int L) {
  int i = blockIdx.x * blockDim.x + threadIdx.x;
  if (i >= P) return;
  int i64 = flags[0], l64 = flags[1];
  int len = iread(lens_raw, i, l64);
  if (len > L - 1) len = L - 1;
  for (int t = 0; t <= len; ++t) {
    int ch = iread(idx_raw, (long)i * L + t, i64);
    if (ch < 0) ch = 0;
    if (ch >= C) ch = C - 1;
    atomicAdd(&cnt[ch], 1);
  }
}

// histogram of per-path step counts (steps = min(len,L-1)+1 in [1..L])
__global__ __launch_bounds__(256) void len_hist(
    const void* __restrict__ lens_raw, const int* __restrict__ flags,
    int* __restrict__ hist, int P, int L) {
  int i = blockIdx.x * blockDim.x + threadIdx.x;
  if (i >= P) return;
  int len = iread(lens_raw, i, flags[1]);
  if (len > L - 1) len = L - 1;
  if (len < 0) len = 0;  // steps>=1 always (t=0 runs since 0<=len is false only len<0; jax mask: t<=len -> len<0 = no steps)
  atomicAdd(&hist[len], 1);
}

// generic single-block exclusive scan: cnt[0..n) -> rowstart[0..n], cursor copy
__global__ __launch_bounds__(1024) void scan_counts(
    const int* __restrict__ cnt, int* __restrict__ rowstart,
    int* __restrict__ cursor, int n) {
  __shared__ int buf[1024];
  __shared__ int carry;
  if (threadIdx.x == 0) carry = 0;
  __syncthreads();
  for (int base = 0; base < n; base += 1024) {
    int i = base + threadIdx.x;
    int v = (i < n) ? cnt[i] : 0;
    buf[threadIdx.x] = v;
    __syncthreads();
    for (int off = 1; off < 1024; off <<= 1) {
      int t = (threadIdx.x >= off) ? buf[threadIdx.x - off] : 0;
      __syncthreads();
      buf[threadIdx.x] += t;
      __syncthreads();
    }
    int excl = buf[threadIdx.x] - v;
    if (i < n) { rowstart[i] = carry + excl; cursor[i] = carry + excl; }
    __syncthreads();
    if (threadIdx.x == 0) carry += buf[1023];
    __syncthreads();
  }
  if (threadIdx.x == 0) rowstart[n] = carry;
}

// entries[slot] = path (CSR fill for channel gather)
__global__ __launch_bounds__(256) void fill_entries(
    const void* __restrict__ idx_raw, const void* __restrict__ lens_raw,
    const int* __restrict__ flags, int* __restrict__ cursor,
    int* __restrict__ entries, int P, int C, int L) {
  int i = blockIdx.x * blockDim.x + threadIdx.x;
  if (i >= P) return;
  int i64 = flags[0], l64 = flags[1];
  int len = iread(lens_raw, i, l64);
  if (len > L - 1) len = L - 1;
  for (int t = 0; t <= len; ++t) {
    int ch = iread(idx_raw, (long)i * L + t, i64);
    if (ch < 0) ch = 0;
    if (ch >= C) ch = C - 1;
    int slot = atomicAdd(&cursor[ch], 1);
    entries[slot] = i;
  }
}

// order[slot] = path, grouped by len -> waves become len-homogeneous
__global__ __launch_bounds__(256) void fill_order(
    const void* __restrict__ lens_raw, const int* __restrict__ flags,
    int* __restrict__ lcursor, int* __restrict__ order, int P, int L) {
  int i = blockIdx.x * blockDim.x + threadIdx.x;
  if (i >= P) return;
  int len = iread(lens_raw, i, flags[1]);
  if (len > L - 1) len = L - 1;
  if (len < 0) len = 0;
  int slot = atomicAdd(&lcursor[len], 1);
  order[slot] = i;
}

// ---- per-outer-step kernels (guarded by device-side num_steps) ----

// GRU scan over t with h in registers; processes paths in len-sorted order.
// __launch_bounds__(256,4): cap VGPR at 128 -> 4 waves/SIMD (was 224/2 waves).
__global__ __launch_bounds__(256, 4) void path_step(
    const float* __restrict__ c_state, float* __restrict__ p_state,
    const void* __restrict__ idx_raw, const void* __restrict__ lens_raw,
    const int* __restrict__ flags, const int* __restrict__ order,
    const float* __restrict__ Wi, const float* __restrict__ Wh,
    const float* __restrict__ bi, const float* __restrict__ bh,
    int P, int C, int L, const int* __restrict__ ns_ptr, int use_mem, int s) {
  int ns = use_mem ? *ns_ptr : 5;
  if (ns < 1 || ns > MAX_OUTER) ns = 5;
  if (s >= ns) return;
  int tid = blockIdx.x * blockDim.x + threadIdx.x;
  if (tid >= P) return;
  int i = order[tid];
  int i64 = flags[0], l64 = flags[1];
  int len = iread(lens_raw, i, l64);
  if (len > L - 1) len = L - 1;

  float h[FF];
  const float4* pp = (const float4*)(p_state + (size_t)i * FF);
#pragma unroll
  for (int q = 0; q < FF / 4; ++q) {
    float4 v = pp[q];
    h[q * 4 + 0] = v.x; h[q * 4 + 1] = v.y; h[q * 4 + 2] = v.z; h[q * 4 + 3] = v.w;
  }

#pragma unroll 1
  for (int t = 0; t <= len && t < L; ++t) {
    int ch = iread(idx_raw, (long)i * L + t, i64);
    if (ch < 0) ch = 0;
    if (ch >= C) ch = C - 1;  // jax gather clips
    float x[FF];
    const float4* cp = (const float4*)(c_state + (size_t)ch * FF);
#pragma unroll
    for (int q = 0; q < FF / 4; ++q) {
      float4 v = cp[q];
      x[q * 4 + 0] = v.x; x[q * 4 + 1] = v.y; x[q * 4 + 2] = v.z; x[q * 4 + 3] = v.w;
    }
    gru_gates(Wi, Wh, bi, bh, x, h);
  }

  float4* op = (float4*)(p_state + (size_t)i * FF);
#pragma unroll
  for (int q = 0; q < FF / 4; ++q) {
    float4 v;
    v.x = h[q * 4 + 0]; v.y = h[q * 4 + 1]; v.z = h[q * 4 + 2]; v.w = h[q * 4 + 3];
    op[q] = v;
  }
}

// atomic-free segment sum: 32 lanes per channel sum contributor p-rows
__global__ __launch_bounds__(256) void agg_gather(
    const float* __restrict__ p_state, const int* __restrict__ rowstart,
    const int* __restrict__ entries, float* __restrict__ agg,
    int C, const int* __restrict__ ns_ptr, int use_mem, int s) {
  int ns = use_mem ? *ns_ptr : 5;
  if (ns < 1 || ns > MAX_OUTER) ns = 5;
  if (s >= ns) return;
  int c = blockIdx.x * 8 + (threadIdx.x >> 5);
  int j = threadIdx.x & 31;
  if (c >= C) return;
  int rs = rowstart[c], re = rowstart[c + 1];
  float acc = 0.0f;
  for (int e = rs; e < re; ++e) {
    int path = entries[e];
    acc += p_state[(size_t)path * FF + j];
  }
  agg[(size_t)c * FF + j] = acc;
}

__global__ __launch_bounds__(256) void chan_step(
    float* __restrict__ c_state, const float* __restrict__ agg,
    const float* __restrict__ Wi, const float* __restrict__ Wh,
    const float* __restrict__ bi, const float* __restrict__ bh,
    int C, const int* __restrict__ ns_ptr, int use_mem, int s) {
  int ns = use_mem ? *ns_ptr : 5;
  if (ns < 1 || ns > MAX_OUTER) ns = 5;
  if (s >= ns) return;
  int i = blockIdx.x * blockDim.x + threadIdx.x;
  if (i >= C) return;

  float x[FF], h[FF];
  const float4* apv = (const float4*)(agg + (size_t)i * FF);
  const float4* cpv = (const float4*)(c_state + (size_t)i * FF);
#pragma unroll
  for (int q = 0; q < FF / 4; ++q) {
    float4 a = apv[q];
    x[q * 4 + 0] = a.x; x[q * 4 + 1] = a.y; x[q * 4 + 2] = a.z; x[q * 4 + 3] = a.w;
    float4 c = cpv[q];
    h[q * 4 + 0] = c.x; h[q * 4 + 1] = c.y; h[q * 4 + 2] = c.z; h[q * 4 + 3] = c.w;
  }
  gru_gates(Wi, Wh, bi, bh, x, h);
  float4* op = (float4*)(c_state + (size_t)i * FF);
#pragma unroll
  for (int q = 0; q < FF / 4; ++q) {
    float4 v;
    v.x = h[q * 4 + 0]; v.y = h[q * 4 + 1]; v.z = h[q * 4 + 2]; v.w = h[q * 4 + 3];
    op[q] = v;
  }
}

__global__ void beacon(float* out, int code) {
  out[0] = (float)(1024 * (64 + code));
}

extern "C" void kernel_launch(void* const* d_in, const int* in_sizes, int n_in,
                              void* d_out, int out_size, void* d_ws, size_t ws_size,
                              hipStream_t stream) {
  int base = 5, use_mem = 1;
  if (n_in == 16) { base = 4; use_mem = 0; }
  const float* path_raw = (const float*)d_in[0];
  const float* chan_raw = (const float*)d_in[1];
  const void* idx_raw  = d_in[2];
  const void* lens_raw = d_in[3];
  const int* ns_ptr = use_mem ? (const int*)d_in[4] : (const int*)d_in[0];
  const float* Wp  = (const float*)d_in[base + 0];
  const float* bp  = (const float*)d_in[base + 1];
  const float* Wc  = (const float*)d_in[base + 2];
  const float* bc  = (const float*)d_in[base + 3];
  const float* Wi1 = (const float*)d_in[base + 4];
  const float* Wh1 = (const float*)d_in[base + 5];
  const float* bi1 = (const float*)d_in[base + 6];
  const float* bh1 = (const float*)d_in[base + 7];
  const float* Wi2 = (const float*)d_in[base + 8];
  const float* Wh2 = (const float*)d_in[base + 9];
  const float* bi2 = (const float*)d_in[base + 10];
  const float* bh2 = (const float*)d_in[base + 11];

  long P = in_sizes[0] / DIN;
  long C = in_sizes[1] / DIN;
  long L = (P > 0) ? (in_sizes[2] / P) : 8;
  long PL = P * L;

  int anomaly = 0;
  if (n_in != 17 && n_in != 16) anomaly |= 1;
  if (P <= 0 || C <= 0 || L < 1 || L > 64) anomaly |= 2;
  if (P > 0 && in_sizes[3] != (int)P) anomaly |= 4;
  if ((long)out_size != (P + C) * FF) anomaly |= 8;

  // p_state and c_state live DIRECTLY in d_out (output is fp32, same layout)
  float* out_f   = (float*)d_out;
  float* p_state = out_f;                     // P*FF floats
  float* c_state = out_f + (size_t)P * FF;    // C*FF floats

  // workspace: flags | rowstart[C+1] | cursor[C] | entries[PL] | agg[C*FF]
  //          | order[P] | lhist[L+1] | lrow[L+2]
  int* flags    = (int*)d_ws;
  int* rowstart = flags + 16;
  int* cursor   = rowstart + (C + 1);
  int* entries  = cursor + C;
  float* agg    = (float*)(entries + PL);
  int* order    = (int*)(agg + (size_t)C * FF);
  int* lhist    = order + P;
  int* lrow     = lhist + (L + 1);
  size_t need = ((size_t)16 + (C + 1) + C + PL + (size_t)C * FF +
                 P + (L + 1) + (L + 2)) * 4;
  if (ws_size < need) anomaly |= 16;

  detect_dtypes<<<1, 256, 0, stream>>>((const int*)idx_raw, (const int*)lens_raw, flags);

  // initial projections straight into d_out
  init_proj<<<(int)((P + 255) / 256), 256, 0, stream>>>(path_raw, Wp, bp, p_state, (int)P);
  init_proj<<<(int)((C + 255) / 256), 256, 0, stream>>>(chan_raw, Wc, bc, c_state, (int)C);

  // CSR build + len-sorted order (idx/lens invariant across outer steps)
  hipMemsetAsync(cursor, 0, (size_t)C * sizeof(int), stream);
  hipMemsetAsync(lhist, 0, (size_t)(L + 1) * sizeof(int), stream);
  count_contribs<<<(int)((P + 255) / 256), 256, 0, stream>>>(
      idx_raw, lens_raw, flags, cursor, (int)P, (int)C, (int)L);
  scan_counts<<<1, 1024, 0, stream>>>(cursor, rowstart, cursor, (int)C);
  fill_entries<<<(int)((P + 255) / 256), 256, 0, stream>>>(
      idx_raw, lens_raw, flags, cursor, entries, (int)P, (int)C, (int)L);
  len_hist<<<(int)((P + 255) / 256), 256, 0, stream>>>(
      lens_raw, flags, lhist, (int)P, (int)L);
  scan_counts<<<1, 1024, 0, stream>>>(lhist, lrow, lhist, (int)L + 1);
  fill_order<<<(int)((P + 255) / 256), 256, 0, stream>>>(
      lens_raw, flags, lhist, order, (int)P, (int)L);

  for (int s = 0; s < MAX_OUTER; ++s) {
    path_step<<<(int)((P + 255) / 256), 256, 0, stream>>>(
        c_state, p_state, idx_raw, lens_raw, flags, order,
        Wi1, Wh1, bi1, bh1, (int)P, (int)C, (int)L, ns_ptr, use_mem, s);
    agg_gather<<<(int)((C + 7) / 8), 256, 0, stream>>>(
        p_state, rowstart, entries, agg, (int)C, ns_ptr, use_mem, s);
    chan_step<<<(int)((C + 255) / 256), 256, 0, stream>>>(
        c_state, agg, Wi2, Wh2, bi2, bh2, (int)C, ns_ptr, use_mem, s);
  }

  if (anomaly) beacon<<<1, 1, 0, stream>>>(out_f, anomaly);
}